// Round 7
// baseline (64.148 us; speedup 1.0000x reference)
//
#include <hip/hip_runtime.h>

// Problem constants (from the JAX reference)
constexpr int B = 4;
constexpr int L = 4096;
constexpr int D = 2048;
constexpr float EPS = 1e-5f;

constexpr int CL = 8;            // output rows per thread in conv pass
constexpr int NR = CL + 3;       // rows loaded incl. causal halo = 11
constexpr int NCHUNK = L / CL;   // 512
constexpr int NWG2 = NCHUNK * B; // 2048 conv blocks (divisible by 8 XCDs)

typedef float floatx4 __attribute__((ext_vector_type(4)));

// ---------------------------------------------------------------------------
// Kernel 1: inv_rms per row; ONE WAVE per row, no LDS, no barriers.
// Block = 256 threads = 4 waves = 4 rows. Lane reads 8 coalesced float4s.
// ---------------------------------------------------------------------------
__global__ __launch_bounds__(256) void rms_kernel(const float* __restrict__ x,
                                                  float* __restrict__ inv_rms) {
    const int wave = threadIdx.x >> 6;
    const int lane = threadIdx.x & 63;
    const int row = blockIdx.x * 4 + wave;      // [0, B*L)

    const floatx4* xr = reinterpret_cast<const floatx4*>(x + (size_t)row * D);

    floatx4 v[8];
    #pragma unroll
    for (int i = 0; i < 8; ++i) v[i] = xr[lane + i * 64];

    float s = 0.0f;
    #pragma unroll
    for (int i = 0; i < 8; ++i)
        s += v[i].x * v[i].x + v[i].y * v[i].y + v[i].z * v[i].z + v[i].w * v[i].w;

    #pragma unroll
    for (int off = 32; off > 0; off >>= 1)
        s += __shfl_down(s, off, 64);

    if (lane == 0)
        inv_rms[row] = rsqrtf(s * (1.0f / D) + EPS);
}

// ---------------------------------------------------------------------------
// Kernel 2: normalize -> causal conv K=4 -> SiLU. ZERO barriers, ZERO LDS.
// Each thread: one float4 channel slice, CL=8 output rows, 11 independent
// row loads in flight. inv_rms loads are wave-uniform (scalar path).
// ---------------------------------------------------------------------------
__global__ __launch_bounds__(512) void conv_kernel(const float* __restrict__ x,
                                                   const float* __restrict__ nw,
                                                   const float* __restrict__ cw,
                                                   const float* __restrict__ inv_rms,
                                                   float* __restrict__ out) {
    const int t = threadIdx.x;          // 0..511
    // XCD-aware swizzle: consecutive work ids (adjacent L-chunks sharing halo
    // rows) land on the same XCD's L2. NWG2 % 8 == 0 -> bijective.
    const int bid = blockIdx.x;
    const int swz = (bid & 7) * (NWG2 / 8) + (bid >> 3);
    const int b = swz / NCHUNK;
    const int chunk = swz % NCHUNK;
    const int l0 = chunk * CL;
    const int d = t * 4;

    const float* xb = x + (size_t)b * L * D + d;
    float* ob = out + (size_t)b * L * D + d;
    const float* ir = inv_rms + (size_t)b * L;

    // Fold norm_weight into conv weights: wn[k] = cw[k,:] * nw
    const floatx4 nwv = *reinterpret_cast<const floatx4*>(nw + d);
    floatx4 wn[4];
    #pragma unroll
    for (int k = 0; k < 4; ++k)
        wn[k] = *reinterpret_cast<const floatx4*>(cw + k * D + d) * nwv;

    // Issue all 11 row loads (independent, stay in flight together)
    floatx4 hx[NR];
    #pragma unroll
    for (int j = 0; j < NR; ++j) {
        const int l = l0 - 3 + j;
        if (l >= 0)
            hx[j] = *reinterpret_cast<const floatx4*>(xb + (size_t)l * D);
        else
            hx[j] = (floatx4)0.0f;
    }

    // Per-row inv_rms (wave-uniform -> scalar loads), applied at use
    float irv[NR];
    #pragma unroll
    for (int j = 0; j < NR; ++j) {
        const int l = l0 - 3 + j;
        irv[j] = (l >= 0) ? ir[l] : 0.0f;
    }
    #pragma unroll
    for (int j = 0; j < NR; ++j) hx[j] *= irv[j];

    // Conv + SiLU + nt-store
    #pragma unroll
    for (int li = 0; li < CL; ++li) {
        floatx4 y = wn[0] * hx[li]     + wn[1] * hx[li + 1]
                  + wn[2] * hx[li + 2] + wn[3] * hx[li + 3];
        floatx4 sg;
        sg.x = 1.0f / (1.0f + __expf(-y.x));
        sg.y = 1.0f / (1.0f + __expf(-y.y));
        sg.z = 1.0f / (1.0f + __expf(-y.z));
        sg.w = 1.0f / (1.0f + __expf(-y.w));
        y *= sg;
        __builtin_nontemporal_store(y,
            reinterpret_cast<floatx4*>(ob + (size_t)(l0 + li) * D));
    }
}

extern "C" void kernel_launch(void* const* d_in, const int* in_sizes, int n_in,
                              void* d_out, int out_size, void* d_ws, size_t ws_size,
                              hipStream_t stream) {
    const float* x  = (const float*)d_in[0];   // (B, L, D) fp32
    const float* nw = (const float*)d_in[1];   // (D,) fp32
    const float* cw = (const float*)d_in[2];   // (K, 1, D) fp32
    float* out = (float*)d_out;                // (B, L, D) fp32
    float* inv_rms = (float*)d_ws;             // B*L floats = 64 KB scratch

    rms_kernel<<<B * L / 4, 256, 0, stream>>>(x, inv_rms);
    conv_kernel<<<NWG2, 512, 0, stream>>>(x, nw, cw, inv_rms, out);
}

// Round 8
// 51.241 us; speedup vs baseline: 1.2519x; 1.2519x over previous
//
#include <hip/hip_runtime.h>

// Problem constants (from the JAX reference)
constexpr int B = 4;
constexpr int L = 4096;
constexpr int D = 2048;
constexpr float EPS = 1e-5f;

constexpr int CL = 32;          // output rows per block (per thread)
constexpr int R  = 8;           // rows per barrier group
constexpr int NG = CL / R;      // 4 main groups
constexpr int NW = 8;           // waves per block (512 threads)
constexpr int NCHUNK = L / CL;  // 128
constexpr int NWG = NCHUNK * B; // 512 blocks (divisible by 8 XCDs)

typedef float floatx4 __attribute__((ext_vector_type(4)));

// Barrier that only drains LDS ops (lgkmcnt), NOT outstanding global loads
// (vmcnt): prefetched loads stay in flight across it.
__device__ __forceinline__ void light_barrier() {
    asm volatile("s_waitcnt lgkmcnt(0)" ::: "memory");
    __builtin_amdgcn_s_barrier();
    asm volatile("" ::: "memory");
}

__device__ __forceinline__ float dot4(floatx4 v) {
    return v.x * v.x + v.y * v.y + v.z * v.z + v.w * v.w;
}

// ---------------------------------------------------------------------------
// Fully fused: RMSNorm -> causal depthwise conv (K=4) -> SiLU, single pass.
// Block covers all of D (512 threads x float4) for CL=32 consecutive rows:
// halo re-read is 3/32 (vs 3/16 before) -> 278 MB total issued traffic.
// R=8 rows per light barrier; next group's loads prefetched before the
// reduce so their latency hides under reduce+barrier+finish.
// ---------------------------------------------------------------------------
__global__ __launch_bounds__(512, 4) void fused_kernel(const float* __restrict__ x,
                                                       const float* __restrict__ nw,
                                                       const float* __restrict__ cw,
                                                       float* __restrict__ out) {
    const int t = threadIdx.x;          // 0..511
    const int wave = t >> 6;
    const int lane = t & 63;

    // XCD-aware swizzle (NWG % 8 == 0 -> bijective): adjacent chunks share
    // halo rows on the same XCD's L2.
    const int bid = blockIdx.x;
    const int swz = (bid & 7) * (NWG / 8) + (bid >> 3);
    const int b = swz / NCHUNK;
    const int chunk = swz % NCHUNK;
    const int l0 = chunk * CL;
    const int d = t * 4;

    const float* xb = x + (size_t)b * L * D + d;
    float* ob = out + (size_t)b * L * D + d;

    __shared__ __align__(16) float s_red[2][R][NW];   // 512 B

    // Fold norm_weight into conv weights: wn[k] = cw[k,:] * nw
    const floatx4 nwv = *reinterpret_cast<const floatx4*>(nw + d);
    floatx4 wn[4];
    #pragma unroll
    for (int k = 0; k < 4; ++k)
        wn[k] = *reinterpret_cast<const floatx4*>(cw + k * D + d) * nwv;

    // ---- Issue halo (3) + first main group (8) loads together: 11 in flight
    floatx4 hx[3];
    #pragma unroll
    for (int j = 0; j < 3; ++j) {
        const int l = l0 - 3 + j;
        hx[j] = (floatx4)0.0f;
        if (l >= 0)
            hx[j] = *reinterpret_cast<const floatx4*>(xb + (size_t)l * D);
    }
    floatx4 cur[R], nxt[R];
    #pragma unroll
    for (int r = 0; r < R; ++r)
        cur[r] = *reinterpret_cast<const floatx4*>(xb + (size_t)(l0 + r) * D);

    // ---- Halo group: 3 reduces -> buf0, one barrier, finish -> win ----
    float win_x[3], win_y[3], win_z[3], win_w[3];
    {
        #pragma unroll
        for (int j = 0; j < 3; ++j) {
            float s = dot4(hx[j]);
            #pragma unroll
            for (int off = 32; off > 0; off >>= 1)
                s += __shfl_down(s, off, 64);
            if (lane == 0) s_red[0][j][wave] = s;
        }
        light_barrier();
        #pragma unroll
        for (int j = 0; j < 3; ++j) {
            floatx4 p0 = *reinterpret_cast<const floatx4*>(&s_red[0][j][0]);
            floatx4 p1 = *reinterpret_cast<const floatx4*>(&s_red[0][j][4]);
            float tot = ((p0.x + p0.y) + (p0.z + p0.w))
                      + ((p1.x + p1.y) + (p1.z + p1.w));
            const float irms = rsqrtf(tot * (1.0f / D) + EPS);
            floatx4 c = hx[j] * irms;
            win_x[j] = c.x; win_y[j] = c.y; win_z[j] = c.z; win_w[j] = c.w;
        }
    }

    // ---- Main: NG groups of R rows, one light barrier per group ----
    #pragma unroll 1
    for (int g = 0; g < NG; ++g) {
        const int par = (g + 1) & 1;    // halo used buffer 0

        // Prefetch next group's rows first (latency hides under this group)
        if (g + 1 < NG) {
            #pragma unroll
            for (int r = 0; r < R; ++r)
                nxt[r] = *reinterpret_cast<const floatx4*>(
                             xb + (size_t)(l0 + (g + 1) * R + r) * D);
        }

        // 8 independent reduce chains
        #pragma unroll
        for (int r = 0; r < R; ++r) {
            float s = dot4(cur[r]);
            #pragma unroll
            for (int off = 32; off > 0; off >>= 1)
                s += __shfl_down(s, off, 64);
            if (lane == 0) s_red[par][r][wave] = s;
        }

        light_barrier();

        #pragma unroll
        for (int r = 0; r < R; ++r) {
            floatx4 p0 = *reinterpret_cast<const floatx4*>(&s_red[par][r][0]);
            floatx4 p1 = *reinterpret_cast<const floatx4*>(&s_red[par][r][4]);
            float tot = ((p0.x + p0.y) + (p0.z + p0.w))
                      + ((p1.x + p1.y) + (p1.z + p1.w));
            const float irms = rsqrtf(tot * (1.0f / D) + EPS);
            floatx4 c = cur[r] * irms;

            floatx4 y;
            y.x = wn[0].x * win_x[0] + wn[1].x * win_x[1] + wn[2].x * win_x[2] + wn[3].x * c.x;
            y.y = wn[0].y * win_y[0] + wn[1].y * win_y[1] + wn[2].y * win_y[2] + wn[3].y * c.y;
            y.z = wn[0].z * win_z[0] + wn[1].z * win_z[1] + wn[2].z * win_z[2] + wn[3].z * c.z;
            y.w = wn[0].w * win_w[0] + wn[1].w * win_w[1] + wn[2].w * win_w[2] + wn[3].w * c.w;

            floatx4 sg;
            sg.x = 1.0f / (1.0f + __expf(-y.x));
            sg.y = 1.0f / (1.0f + __expf(-y.y));
            sg.z = 1.0f / (1.0f + __expf(-y.z));
            sg.w = 1.0f / (1.0f + __expf(-y.w));
            y *= sg;
            __builtin_nontemporal_store(y,
                reinterpret_cast<floatx4*>(ob + (size_t)(l0 + g * R + r) * D));

            // slide window
            win_x[0] = win_x[1]; win_x[1] = win_x[2]; win_x[2] = c.x;
            win_y[0] = win_y[1]; win_y[1] = win_y[2]; win_y[2] = c.y;
            win_z[0] = win_z[1]; win_z[1] = win_z[2]; win_z[2] = c.z;
            win_w[0] = win_w[1]; win_w[1] = win_w[2]; win_w[2] = c.w;
        }

        #pragma unroll
        for (int r = 0; r < R; ++r) cur[r] = nxt[r];
    }
}

extern "C" void kernel_launch(void* const* d_in, const int* in_sizes, int n_in,
                              void* d_out, int out_size, void* d_ws, size_t ws_size,
                              hipStream_t stream) {
    const float* x  = (const float*)d_in[0];   // (B, L, D) fp32
    const float* nw = (const float*)d_in[1];   // (D,) fp32
    const float* cw = (const float*)d_in[2];   // (K, 1, D) fp32
    float* out = (float*)d_out;                // (B, L, D) fp32

    fused_kernel<<<NWG, 512, 0, stream>>>(x, nw, cw, out);
}

// Round 9
// 48.859 us; speedup vs baseline: 1.3129x; 1.0488x over previous
//
#include <hip/hip_runtime.h>

// Problem constants (from the JAX reference)
constexpr int B = 4;
constexpr int L = 4096;
constexpr int D = 2048;
constexpr float EPS = 1e-5f;

constexpr int CL = 32;         // L-rows per block (R5 had 16; only change)
constexpr int R  = 4;          // rows per barrier group
constexpr int NG = CL / R;     // 8 main groups
constexpr int NW = 8;          // waves per block (512 threads)
constexpr int NCHUNK = L / CL; // 128
constexpr int NWG = NCHUNK * B;// 512 blocks (divisible by 8 XCDs)

typedef float floatx4 __attribute__((ext_vector_type(4)));

__device__ __forceinline__ void load4(const float* __restrict__ p, float r[4]) {
    floatx4 v = *reinterpret_cast<const floatx4*>(p);
    r[0] = v.x; r[1] = v.y; r[2] = v.z; r[3] = v.w;
}

// Barrier that only drains LDS ops (lgkmcnt), NOT outstanding global loads
// (vmcnt). The prefetched next-group loads stay in flight across it.
__device__ __forceinline__ void light_barrier() {
    asm volatile("s_waitcnt lgkmcnt(0)" ::: "memory");
    __builtin_amdgcn_s_barrier();
    asm volatile("" ::: "memory");
}

// ---------------------------------------------------------------------------
// Fully fused: RMSNorm -> causal depthwise conv (K=4) -> SiLU, single pass.
// Identical structure to the best (R5) kernel; only CL changed 16 -> 32
// (halo re-read 3/16 -> 3/32 of x).
// ---------------------------------------------------------------------------
__global__ __launch_bounds__(512) void fused_kernel(const float* __restrict__ x,
                                                    const float* __restrict__ nw,
                                                    const float* __restrict__ cw,
                                                    float* __restrict__ out) {
    const int t = threadIdx.x;          // 0..511
    const int wave = t >> 6;
    const int lane = t & 63;

    // XCD-aware swizzle: consecutive work ids (adjacent L-chunks, sharing
    // halo rows) land on the same XCD's L2. NWG % 8 == 0 -> bijective.
    const int bid = blockIdx.x;
    const int swz = (bid & 7) * (NWG / 8) + (bid >> 3);
    const int b = swz / NCHUNK;
    const int chunk = swz % NCHUNK;
    const int l0 = chunk * CL;
    const int d = t * 4;

    const float* xb = x + (size_t)b * L * D + d;
    float* ob = out + (size_t)b * L * D + d;

    __shared__ float s_red[2][R][NW];

    float nwv[4], wv[4][4];
    load4(nw + d, nwv);
    #pragma unroll
    for (int k = 0; k < 4; ++k) load4(cw + k * D + d, wv[k]);  // (K,1,D)

    // ---- Halo: rows l0-3 .. l0-1, batched: 3 reduces, ONE barrier ----
    float win[3][4];
    {
        float hx[3][4];
        #pragma unroll
        for (int j = 0; j < 3; ++j) {
            const int l = l0 - 3 + j;
            hx[j][0] = hx[j][1] = hx[j][2] = hx[j][3] = 0.0f;
            if (l >= 0) load4(xb + (size_t)l * D, hx[j]);
            float s = hx[j][0]*hx[j][0] + hx[j][1]*hx[j][1]
                    + hx[j][2]*hx[j][2] + hx[j][3]*hx[j][3];
            #pragma unroll
            for (int off = 32; off > 0; off >>= 1)
                s += __shfl_down(s, off, 64);
            if (lane == 0) s_red[0][j][wave] = s;
        }
        light_barrier();
        #pragma unroll
        for (int j = 0; j < 3; ++j) {
            float tot = 0.0f;
            #pragma unroll
            for (int w = 0; w < NW; ++w) tot += s_red[0][j][w];
            float irms = rsqrtf(tot * (1.0f / D) + EPS);
            #pragma unroll
            for (int i = 0; i < 4; ++i) win[j][i] = hx[j][i] * irms * nwv[i];
        }
    }

    // ---- Main: NG groups of R rows, one light barrier per group ----
    float cur[R][4], nxt[R][4];
    #pragma unroll
    for (int r = 0; r < R; ++r)
        load4(xb + (size_t)(l0 + r) * D, cur[r]);

    #pragma unroll
    for (int g = 0; g < NG; ++g) {
        const int par = (g + 1) & 1;    // halo used buffer 0

        // 4 independent reduce chains
        #pragma unroll
        for (int r = 0; r < R; ++r) {
            float s = cur[r][0]*cur[r][0] + cur[r][1]*cur[r][1]
                    + cur[r][2]*cur[r][2] + cur[r][3]*cur[r][3];
            #pragma unroll
            for (int off = 32; off > 0; off >>= 1)
                s += __shfl_down(s, off, 64);
            if (lane == 0) s_red[par][r][wave] = s;
        }

        // prefetch next group's rows; loads stay in flight across the barrier
        if (g + 1 < NG) {
            #pragma unroll
            for (int r = 0; r < R; ++r)
                load4(xb + (size_t)(l0 + (g + 1) * R + r) * D, nxt[r]);
        }

        light_barrier();

        #pragma unroll
        for (int r = 0; r < R; ++r) {
            float tot = 0.0f;
            #pragma unroll
            for (int w = 0; w < NW; ++w) tot += s_red[par][r][w];
            const float irms = rsqrtf(tot * (1.0f / D) + EPS);

            float c[4], y[4];
            #pragma unroll
            for (int i = 0; i < 4; ++i) {
                c[i] = cur[r][i] * irms * nwv[i];
                y[i] = wv[0][i]*win[0][i] + wv[1][i]*win[1][i]
                     + wv[2][i]*win[2][i] + wv[3][i]*c[i];
                y[i] = y[i] / (1.0f + __expf(-y[i]));   // SiLU
            }
            floatx4 o;
            o.x = y[0]; o.y = y[1]; o.z = y[2]; o.w = y[3];
            __builtin_nontemporal_store(o,
                reinterpret_cast<floatx4*>(ob + (size_t)(l0 + g * R + r) * D));

            #pragma unroll
            for (int i = 0; i < 4; ++i) {
                win[0][i] = win[1][i];
                win[1][i] = win[2][i];
                win[2][i] = c[i];
            }
        }

        #pragma unroll
        for (int r = 0; r < R; ++r)
            #pragma unroll
            for (int i = 0; i < 4; ++i) cur[r][i] = nxt[r][i];
    }
}

extern "C" void kernel_launch(void* const* d_in, const int* in_sizes, int n_in,
                              void* d_out, int out_size, void* d_ws, size_t ws_size,
                              hipStream_t stream) {
    const float* x  = (const float*)d_in[0];   // (B, L, D) fp32
    const float* nw = (const float*)d_in[1];   // (D,) fp32
    const float* cw = (const float*)d_in[2];   // (K, 1, D) fp32
    float* out = (float*)d_out;                // (B, L, D) fp32

    fused_kernel<<<NWG, 512, 0, stream>>>(x, nw, cw, out);
}

// Round 10
// 47.790 us; speedup vs baseline: 1.3423x; 1.0224x over previous
//
#include <hip/hip_runtime.h>

// Problem constants (from the JAX reference)
constexpr int B = 4;
constexpr int L = 4096;
constexpr int D = 2048;
constexpr float EPS = 1e-5f;

constexpr int CL = 32;         // L-rows per block
constexpr int R  = 4;          // rows per barrier group
constexpr int NG = CL / R;     // 8 main groups
constexpr int NW = 8;          // waves per block (512 threads)
constexpr int NCHUNK = L / CL; // 128
constexpr int NWG = NCHUNK * B;// 512 blocks (divisible by 8 XCDs)

typedef float floatx4 __attribute__((ext_vector_type(4)));

__device__ __forceinline__ void load4(const float* __restrict__ p, float r[4]) {
    floatx4 v = *reinterpret_cast<const floatx4*>(p);
    r[0] = v.x; r[1] = v.y; r[2] = v.z; r[3] = v.w;
}

// Barrier that only drains LDS ops (lgkmcnt), NOT outstanding global loads
// (vmcnt): prefetched loads stay in flight across it.
__device__ __forceinline__ void light_barrier() {
    asm volatile("s_waitcnt lgkmcnt(0)" ::: "memory");
    __builtin_amdgcn_s_barrier();
    asm volatile("" ::: "memory");
}

// ---------------------------------------------------------------------------
// Fully fused: RMSNorm -> causal depthwise conv (K=4) -> SiLU, single pass.
// Depth-2 software pipeline: loads for group g+2 are issued while group g
// finishes, so each load has a full group cycle to land. LDS partial slots
// use mod-3 parity (write of slot p for group g+3 is separated from the
// read for group g by two barriers -> race-free).
// ---------------------------------------------------------------------------
__global__ __launch_bounds__(512) void fused_kernel(const float* __restrict__ x,
                                                    const float* __restrict__ nw,
                                                    const float* __restrict__ cw,
                                                    float* __restrict__ out) {
    const int t = threadIdx.x;          // 0..511
    const int wave = t >> 6;
    const int lane = t & 63;

    // XCD-aware swizzle: consecutive work ids (adjacent L-chunks, sharing
    // halo rows) land on the same XCD's L2. NWG % 8 == 0 -> bijective.
    const int bid = blockIdx.x;
    const int swz = (bid & 7) * (NWG / 8) + (bid >> 3);
    const int b = swz / NCHUNK;
    const int chunk = swz % NCHUNK;
    const int l0 = chunk * CL;
    const int d = t * 4;

    const float* xb = x + (size_t)b * L * D + d;
    float* ob = out + (size_t)b * L * D + d;

    __shared__ float s_red[3][R][NW];   // mod-3 parity for main groups
    __shared__ float s_halo[3][NW];

    float nwv[4], wv[4][4];
    load4(nw + d, nwv);
    #pragma unroll
    for (int k = 0; k < 4; ++k) load4(cw + k * D + d, wv[k]);  // (K,1,D)

    // ---- Prologue: issue halo(3) + grp0(4) + grp1(4) loads: 11 in flight
    float hx[3][4];
    #pragma unroll
    for (int j = 0; j < 3; ++j) {
        const int l = l0 - 3 + j;
        hx[j][0] = hx[j][1] = hx[j][2] = hx[j][3] = 0.0f;
        if (l >= 0) load4(xb + (size_t)l * D, hx[j]);
    }
    float cur[R][4], nxt[R][4], nxt2[R][4];
    #pragma unroll
    for (int r = 0; r < R; ++r)
        load4(xb + (size_t)(l0 + r) * D, cur[r]);
    #pragma unroll
    for (int r = 0; r < R; ++r)
        load4(xb + (size_t)(l0 + R + r) * D, nxt[r]);

    // Reduce halo + grp0 together, one barrier
    #pragma unroll
    for (int j = 0; j < 3; ++j) {
        float s = hx[j][0]*hx[j][0] + hx[j][1]*hx[j][1]
                + hx[j][2]*hx[j][2] + hx[j][3]*hx[j][3];
        #pragma unroll
        for (int off = 32; off > 0; off >>= 1)
            s += __shfl_down(s, off, 64);
        if (lane == 0) s_halo[j][wave] = s;
    }
    #pragma unroll
    for (int r = 0; r < R; ++r) {
        float s = cur[r][0]*cur[r][0] + cur[r][1]*cur[r][1]
                + cur[r][2]*cur[r][2] + cur[r][3]*cur[r][3];
        #pragma unroll
        for (int off = 32; off > 0; off >>= 1)
            s += __shfl_down(s, off, 64);
        if (lane == 0) s_red[0][r][wave] = s;
    }
    light_barrier();

    // Finish halo -> window (VALU only)
    float win[3][4];
    #pragma unroll
    for (int j = 0; j < 3; ++j) {
        float tot = 0.0f;
        #pragma unroll
        for (int w = 0; w < NW; ++w) tot += s_halo[j][w];
        float irms = rsqrtf(tot * (1.0f / D) + EPS);
        #pragma unroll
        for (int i = 0; i < 4; ++i) win[j][i] = hx[j][i] * irms * nwv[i];
    }

    // ---- Main loop: finish(g) reads slot g%3 (written in iter g-1);
    //      reduce(g+1) writes slot (g+1)%3; loads for g+2 issued now.
    #pragma unroll
    for (int g = 0; g < NG; ++g) {
        // reduce next group's rows (loaded one full iteration ago)
        if (g + 1 < NG) {
            #pragma unroll
            for (int r = 0; r < R; ++r) {
                float s = nxt[r][0]*nxt[r][0] + nxt[r][1]*nxt[r][1]
                        + nxt[r][2]*nxt[r][2] + nxt[r][3]*nxt[r][3];
                #pragma unroll
                for (int off = 32; off > 0; off >>= 1)
                    s += __shfl_down(s, off, 64);
                if (lane == 0) s_red[(g + 1) % 3][r][wave] = s;
            }
        }

        // issue loads for group g+2 (have reduce+barrier+finish to land)
        if (g + 2 < NG) {
            #pragma unroll
            for (int r = 0; r < R; ++r)
                load4(xb + (size_t)(l0 + (g + 2) * R + r) * D, nxt2[r]);
        }

        light_barrier();

        // finish group g: partials from slot g%3, conv + SiLU + nt-store
        #pragma unroll
        for (int r = 0; r < R; ++r) {
            float tot = 0.0f;
            #pragma unroll
            for (int w = 0; w < NW; ++w) tot += s_red[g % 3][r][w];
            const float irms = rsqrtf(tot * (1.0f / D) + EPS);

            float c[4], y[4];
            #pragma unroll
            for (int i = 0; i < 4; ++i) {
                c[i] = cur[r][i] * irms * nwv[i];
                y[i] = wv[0][i]*win[0][i] + wv[1][i]*win[1][i]
                     + wv[2][i]*win[2][i] + wv[3][i]*c[i];
                y[i] = y[i] / (1.0f + __expf(-y[i]));   // SiLU
            }
            floatx4 o;
            o.x = y[0]; o.y = y[1]; o.z = y[2]; o.w = y[3];
            __builtin_nontemporal_store(o,
                reinterpret_cast<floatx4*>(ob + (size_t)(l0 + g * R + r) * D));

            #pragma unroll
            for (int i = 0; i < 4; ++i) {
                win[0][i] = win[1][i];
                win[1][i] = win[2][i];
                win[2][i] = c[i];
            }
        }

        // rotate row buffers (loop fully unrolled -> pure register renaming)
        #pragma unroll
        for (int r = 0; r < R; ++r)
            #pragma unroll
            for (int i = 0; i < 4; ++i) {
                cur[r][i] = nxt[r][i];
                nxt[r][i] = nxt2[r][i];
            }
    }
}

extern "C" void kernel_launch(void* const* d_in, const int* in_sizes, int n_in,
                              void* d_out, int out_size, void* d_ws, size_t ws_size,
                              hipStream_t stream) {
    const float* x  = (const float*)d_in[0];   // (B, L, D) fp32
    const float* nw = (const float*)d_in[1];   // (D,) fp32
    const float* cw = (const float*)d_in[2];   // (K, 1, D) fp32
    float* out = (float*)d_out;                // (B, L, D) fp32

    fused_kernel<<<NWG, 512, 0, stream>>>(x, nw, cw, out);
}